// Round 6
// baseline (565.404 us; speedup 1.0000x reference)
//
#include <hip/hip_runtime.h>

typedef short short8 __attribute__((ext_vector_type(8)));
typedef float floatx4 __attribute__((ext_vector_type(4)));

#define LEAKY(v) ((v) >= 0.0f ? (v) : 0.01f * (v))

constexpr int D = 256;  // in = hid = out = 256

__device__ __forceinline__ short f2bf(float x) {
  unsigned u = __float_as_uint(x);
  u += 0x7fffu + ((u >> 16) & 1u);  // RNE (finite inputs)
  return (short)(u >> 16);
}
__device__ __forceinline__ float bf2f(short s) {
  return __uint_as_float(((unsigned)(unsigned short)s) << 16);
}

// ---- W transpose+convert: Wt[n][k] = bf16(Wsrc[k][n]), 3 matrices ----------
__global__ void transpose_w(const float* __restrict__ W1,
                            const float* __restrict__ W2,
                            const float* __restrict__ Wl,
                            short* __restrict__ Wt) {
  __shared__ float t[32][33];
  const float* src = (blockIdx.z == 0) ? W1 : (blockIdx.z == 1) ? W2 : Wl;
  short* dst = Wt + (size_t)blockIdx.z * D * D;
  int tx = threadIdx.x, ty = threadIdx.y;
  t[ty][tx] = src[(size_t)(blockIdx.y * 32 + ty) * D + blockIdx.x * 32 + tx];
  __syncthreads();
  dst[(size_t)(blockIdx.x * 32 + ty) * D + blockIdx.y * 32 + tx] =
      f2bf(t[tx][ty]);
}

// ---- streaming strip MFMA GEMM: C[M,256] = A[M,256] @ Wt^T (+epilogue) -----
// Zero LDS, zero barriers. 512 thr = 8 waves; per strip (16 rows) wave w owns
// cols w*32..+31. B frags (64 VGPR): ALL 16 loads issued, THEN 16 volatile
// pins (r5 idiom: one latency, remat impossible afterwards; r1's VGPR=64
// proved unpinned B is re-loaded from global per MFMA; r4's pins-between-
// loads serialized them). A streamed to regs, 8 independent loads/lane, NO
// pins (r4 lesson). __launch_bounds__(512,4) -> <=128 VGPR -> 2 blocks/CU =
// 16 independent waves/CU, ~128KB/CU loads in flight, no sync anywhere.
// Persistent grid (512) amortizes the B-load; ~12 strips/block.
template <bool A_F32, bool ADD_ROW, bool FINAL>
__global__ __launch_bounds__(512, 4) void gemm_stream(
    const void* __restrict__ Avoid, const short* __restrict__ Wt,
    const float* __restrict__ R, const int* __restrict__ batch,
    const float* __restrict__ bias, void* __restrict__ Cvoid, int M,
    int nStrips) {
  const int tid = threadIdx.x;
  const int l = tid & 63, w = tid >> 6, lm = l & 15, q = l >> 4;
  const int ncol0 = w * 32;

  // resident B fragments: 2 n-frags x 8 k-frags, 16B/lane -> 64 VGPR
  short8 bf[2][8];
#pragma unroll
  for (int j = 0; j < 2; j++)
#pragma unroll
    for (int kk = 0; kk < 8; kk++)
      bf[j][kk] = *(const short8*)(Wt + (size_t)(ncol0 + j * 16 + lm) * D +
                                   kk * 32 + q * 8);
#pragma unroll
  for (int j = 0; j < 2; j++)
#pragma unroll
    for (int kk = 0; kk < 8; kk++)
      asm volatile("" : "+v"(bf[j][kk]));  // pin AFTER all loads issued

  for (int sp = blockIdx.x; sp < nStrips; sp += gridDim.x) {
    const int row = sp * 16 + lm;          // this lane's A row
    const int rl = row < M ? row : M - 1;  // clamp (stores guarded)

    short8 a[8];  // lane holds A[row][kk*32 + q*8 .. +7], kk = 0..7
    if (A_F32) {
      const float* ap = (const float*)Avoid + (size_t)rl * D + q * 8;
#pragma unroll
      for (int kk = 0; kk < 8; kk++) {
        float4 v0 = *(const float4*)(ap + (size_t)kk * 32);
        float4 v1 = *(const float4*)(ap + (size_t)kk * 32 + 4);
        short8 sv;
        sv[0] = f2bf(v0.x); sv[1] = f2bf(v0.y); sv[2] = f2bf(v0.z); sv[3] = f2bf(v0.w);
        sv[4] = f2bf(v1.x); sv[5] = f2bf(v1.y); sv[6] = f2bf(v1.z); sv[7] = f2bf(v1.w);
        a[kk] = sv;
      }
    } else {
      const short* ap = (const short*)Avoid + (size_t)rl * D + q * 8;
#pragma unroll
      for (int kk = 0; kk < 8; kk++) a[kk] = *(const short8*)(ap + (size_t)kk * 32);
    }

    floatx4 acc[2];
    acc[0] = (floatx4){0.f, 0.f, 0.f, 0.f};
    acc[1] = (floatx4){0.f, 0.f, 0.f, 0.f};
#pragma unroll
    for (int kk = 0; kk < 8; kk++)
#pragma unroll
      for (int j = 0; j < 2; j++)
        acc[j] = __builtin_amdgcn_mfma_f32_16x16x32_bf16(bf[j][kk], a[kk],
                                                         acc[j], 0, 0, 0);

    // lane holds: row = sp*16+lm, cols ncol0 + j*16 + q*4 .. +3
    if (row < M) {
      int rb = 0;
      if (ADD_ROW) rb = batch[row];
#pragma unroll
      for (int j = 0; j < 2; j++) {
        const int col0 = ncol0 + j * 16 + q * 4;
        float c0 = acc[j][0], c1 = acc[j][1], c2 = acc[j][2], c3 = acc[j][3];
        if (ADD_ROW) {
          float4 rv = *(const float4*)(R + (size_t)rb * D + col0);
          c0 += rv.x; c1 += rv.y; c2 += rv.z; c3 += rv.w;
        }
        if (!FINAL) {
          uint2 o;
          o.x = (unsigned)(unsigned short)f2bf(c0) |
                ((unsigned)(unsigned short)f2bf(c1) << 16);
          o.y = (unsigned)(unsigned short)f2bf(c2) |
                ((unsigned)(unsigned short)f2bf(c3) << 16);
          *(uint2*)((short*)Cvoid + (size_t)row * D + col0) = o;
        } else {
          float4 bv = *(const float4*)(bias + col0);  // L2-hot, saves 8 VGPR
          c0 += bv.x; c1 += bv.y; c2 += bv.z; c3 += bv.w;
          c0 = LEAKY(c0); c1 = LEAKY(c1); c2 = LEAKY(c2); c3 = LEAKY(c3);
          float4 o = {c0, c1, c2, c3};
          *(float4*)((float*)Cvoid + (size_t)row * D + col0) = o;
        }
      }
    }
  }
}

// ---------------- CSR build --------------------------------------------------
__global__ void count_dst(const int* __restrict__ dst, int* __restrict__ offs,
                          int E) {
  int e = blockIdx.x * 256 + threadIdx.x;
  if (e < E) atomicAdd(&offs[dst[e]], 1);
}

__global__ void scan_blocks(int* __restrict__ offs, int* __restrict__ bsums,
                            int n) {
  __shared__ int tmp[256];
  int i = blockIdx.x * 256 + threadIdx.x;
  int v = (i < n) ? offs[i] : 0;
  tmp[threadIdx.x] = v;
  __syncthreads();
  for (int off = 1; off < 256; off <<= 1) {
    int t = (threadIdx.x >= off) ? tmp[threadIdx.x - off] : 0;
    __syncthreads();
    tmp[threadIdx.x] += t;
    __syncthreads();
  }
  if (i < n) offs[i] = tmp[threadIdx.x] - v;
  if (threadIdx.x == 255) bsums[blockIdx.x] = tmp[255];
}

__global__ void scan_sums(int* __restrict__ bs, int nb) {
  __shared__ int tmp[1024];
  int v = (threadIdx.x < nb) ? bs[threadIdx.x] : 0;
  tmp[threadIdx.x] = v;
  __syncthreads();
  for (int off = 1; off < 1024; off <<= 1) {
    int t = (threadIdx.x >= off) ? tmp[threadIdx.x - off] : 0;
    __syncthreads();
    tmp[threadIdx.x] += t;
    __syncthreads();
  }
  if (threadIdx.x < nb) bs[threadIdx.x] = tmp[threadIdx.x] - v;
}

__global__ void add_offsets(int* __restrict__ offs, const int* __restrict__ bs,
                            int n, int* __restrict__ cursor) {
  int i = blockIdx.x * 256 + threadIdx.x;
  if (i < n) {
    int o = offs[i] + bs[blockIdx.x];
    offs[i] = o;
    cursor[i] = o;
  }
}

__global__ void fill_buckets(const int* __restrict__ src,
                             const int* __restrict__ dst,
                             const float* __restrict__ vals,
                             int* __restrict__ cursor, int* __restrict__ esrc,
                             float* __restrict__ ew, int E) {
  int e = blockIdx.x * 256 + threadIdx.x;
  if (e < E) {
    int p = atomicAdd(&cursor[dst[e]], 1);
    esrc[p] = src[e];
    ew[p] = vals[e];
  }
}

// ---- gather agg (bf16 in/out): out[n] = bf16(leaky(sum w*H[src] + bias)) ---
// 2-wide edge unroll: two independent H-row gathers in flight per iteration
// (halves the dependent esrc->H latency chain).
__global__ __launch_bounds__(256) void aggregate_bf(
    const short* __restrict__ H, const int* __restrict__ offs,
    const int* __restrict__ esrc, const float* __restrict__ ew,
    const float* __restrict__ bias, short* __restrict__ out, int N, int E) {
  int node = blockIdx.x * 4 + (threadIdx.x >> 6);
  if (node >= N) return;
  int lane = threadIdx.x & 63;
  int beg = offs[node];
  int end = (node == N - 1) ? E : offs[node + 1];
  float a0 = 0.f, a1 = 0.f, a2 = 0.f, a3 = 0.f;
  int i = beg;
  for (; i + 1 < end; i += 2) {
    int s0 = esrc[i], s1 = esrc[i + 1];
    float w0 = ew[i], w1 = ew[i + 1];
    uint2 p0 = ((const uint2*)(H + (size_t)s0 * D))[lane];
    uint2 p1 = ((const uint2*)(H + (size_t)s1 * D))[lane];
    a0 += w0 * bf2f((short)(p0.x & 0xffff)) + w1 * bf2f((short)(p1.x & 0xffff));
    a1 += w0 * bf2f((short)(p0.x >> 16))    + w1 * bf2f((short)(p1.x >> 16));
    a2 += w0 * bf2f((short)(p0.y & 0xffff)) + w1 * bf2f((short)(p1.y & 0xffff));
    a3 += w0 * bf2f((short)(p0.y >> 16))    + w1 * bf2f((short)(p1.y >> 16));
  }
  if (i < end) {
    int s = esrc[i];
    float wv = ew[i];
    uint2 pk = ((const uint2*)(H + (size_t)s * D))[lane];
    a0 += wv * bf2f((short)(pk.x & 0xffff));
    a1 += wv * bf2f((short)(pk.x >> 16));
    a2 += wv * bf2f((short)(pk.y & 0xffff));
    a3 += wv * bf2f((short)(pk.y >> 16));
  }
  float4 b = ((const float4*)bias)[lane];
  a0 = LEAKY(a0 + b.x);
  a1 = LEAKY(a1 + b.y);
  a2 = LEAKY(a2 + b.z);
  a3 = LEAKY(a3 + b.w);
  uint2 o;
  o.x = (unsigned)(unsigned short)f2bf(a0) |
        ((unsigned)(unsigned short)f2bf(a1) << 16);
  o.y = (unsigned)(unsigned short)f2bf(a2) |
        ((unsigned)(unsigned short)f2bf(a3) << 16);
  ((uint2*)(out + (size_t)node * D))[lane] = o;
}

// ---- R1[b,:] = leaky(features[root_b]) @ W2[256:512] (fp32) ----------------
__global__ void root_gemm1(const float* __restrict__ X,
                           const int* __restrict__ root_idx,
                           const float* __restrict__ W2,
                           float* __restrict__ R1) {
  __shared__ float a[D];
  int b = blockIdx.x, j = threadIdx.x;
  int r = root_idx[b];
  a[j] = LEAKY(X[(size_t)r * D + j]);
  __syncthreads();
  float acc = 0.f;
#pragma unroll 8
  for (int k = 0; k < D; k++) acc += a[k] * W2[(size_t)(D + k) * D + j];
  R1[b * D + j] = acc;
}

// ---- R2[b,:] = (agg1[root_b]+b1) @ Wl[256:512]  (recompute agg for root) ---
__global__ void root_gemm2(const short* __restrict__ H,
                           const int* __restrict__ root_idx,
                           const int* __restrict__ offs,
                           const int* __restrict__ esrc,
                           const float* __restrict__ ew,
                           const float* __restrict__ b1,
                           const float* __restrict__ Wl, float* __restrict__ R2,
                           int N, int E) {
  __shared__ float a[D];
  int b = blockIdx.x, j = threadIdx.x;
  int r = root_idx[b];
  int beg = offs[r], end = (r == N - 1) ? E : offs[r + 1];
  float acc = b1[j];
  for (int e = beg; e < end; e++)
    acc += ew[e] * bf2f(H[(size_t)esrc[e] * D + j]);
  a[j] = acc;
  __syncthreads();
  float s = 0.f;
#pragma unroll 8
  for (int k = 0; k < D; k++) s += a[k] * Wl[(size_t)(D + k) * D + j];
  R2[b * D + j] = s;
}

extern "C" void kernel_launch(void* const* d_in, const int* in_sizes, int n_in,
                              void* d_out, int out_size, void* d_ws,
                              size_t ws_size, hipStream_t stream) {
  const float* features = (const float*)d_in[0];  // [N,256]
  const float* values   = (const float*)d_in[1];  // [E]
  const float* W1 = (const float*)d_in[2];        // [256,256]
  const float* b1 = (const float*)d_in[3];        // [256]
  const float* W2 = (const float*)d_in[4];        // [512,256]
  const float* b2 = (const float*)d_in[5];        // [256]
  const float* Wl = (const float*)d_in[6];        // [512,256]
  const float* bl = (const float*)d_in[7];        // [256]
  const int* adjs = (const int*)d_in[8];          // [2,E]
  const int* batch = (const int*)d_in[9];         // [N]
  const int* root_idx = (const int*)d_in[10];     // [B]

  const int N = in_sizes[0] / D;
  const int E = in_sizes[1];
  const int B = in_sizes[10];
  const int* srcI = adjs;
  const int* dstI = adjs + E;

  // workspace layout
  short* bf0 = (short*)d_ws;            // h0_bf, then h2_bf   [N*256]
  short* bf1 = bf0 + (size_t)N * D;     // a1_bf, then a2_bf   [N*256]
  short* Wt = bf1 + (size_t)N * D;      // 3 x [256,256] bf16 (n-major)
  float* R1 = (float*)(Wt + (size_t)3 * D * D);  // [B,256]
  float* R2 = R1 + (size_t)B * D;                // [B,256]
  float* ew = R2 + (size_t)B * D;                // [E]
  int* offs = (int*)(ew + E);                    // [N]
  int* cursor = offs + N;                        // [N]
  int* esrc = cursor + N;                        // [E]
  int* bsums = esrc + E;                         // [<=1024]

  const int nb = (N + 255) / 256;  // 391 <= 1024

  // ---- build dst-CSR (reused by both aggregations + root2) ----
  hipMemsetAsync(offs, 0, (size_t)N * sizeof(int), stream);
  count_dst<<<(E + 255) / 256, 256, 0, stream>>>(dstI, offs, E);
  scan_blocks<<<nb, 256, 0, stream>>>(offs, bsums, N);
  scan_sums<<<1, 1024, 0, stream>>>(bsums, nb);
  add_offsets<<<nb, 256, 0, stream>>>(offs, bsums, N, cursor);
  fill_buckets<<<(E + 255) / 256, 256, 0, stream>>>(srcI, dstI, values, cursor,
                                                    esrc, ew, E);

  // ---- weights -> bf16, transposed to [n][k] ----
  transpose_w<<<dim3(8, 8, 3), dim3(32, 32), 0, stream>>>(W1, W2, Wl, Wt);

  const int nStrips = (N + 15) / 16;  // 6250
  const int ggrid = 512;              // persistent, 2 blocks/CU
  const int aggGrid = (N + 3) / 4;

  // 1) h0 = features @ W1           (fp32 in fused-convert, bf16 out)
  gemm_stream<true, false, false><<<ggrid, 512, 0, stream>>>(
      features, Wt, nullptr, nullptr, nullptr, bf0, N, nStrips);

  // 2) a1 = leaky(segsum(w*h0) + b1)  (bf16)
  aggregate_bf<<<aggGrid, 256, 0, stream>>>(bf0, offs, esrc, ew, b1, bf1, N, E);

  // 3) R1, R2 (root2 recomputes pre-leaky agg1 rows from CSR)
  root_gemm1<<<B, 256, 0, stream>>>(features, root_idx, W2, R1);
  root_gemm2<<<B, 256, 0, stream>>>(bf0, root_idx, offs, esrc, ew, b1, Wl, R2,
                                    N, E);

  // 4) h2 = a1 @ W2_top + R1[batch]   (bf16 in/out; overwrites h0 after root2)
  gemm_stream<false, true, false><<<ggrid, 512, 0, stream>>>(
      bf1, Wt + (size_t)D * D, R1, batch, nullptr, bf0, N, nStrips);

  // 5) a2 = leaky(segsum(w*h2) + b2)  (bf16)
  aggregate_bf<<<aggGrid, 256, 0, stream>>>(bf0, offs, esrc, ew, b2, bf1, N, E);

  // 6) out = leaky(a2 @ Wl_top + R2[batch] + bl)  (fp32 out)
  gemm_stream<false, true, true><<<ggrid, 512, 0, stream>>>(
      bf1, Wt + (size_t)2 * D * D, R2, batch, bl, (float*)d_out, N, nStrips);
}

// Round 7
// 536.089 us; speedup vs baseline: 1.0547x; 1.0547x over previous
//
#include <hip/hip_runtime.h>

typedef short short8 __attribute__((ext_vector_type(8)));
typedef float floatx4 __attribute__((ext_vector_type(4)));

#define LEAKY(v) ((v) >= 0.0f ? (v) : 0.01f * (v))

constexpr int D = 256;  // in = hid = out = 256

__device__ __forceinline__ short f2bf(float x) {
  unsigned u = __float_as_uint(x);
  u += 0x7fffu + ((u >> 16) & 1u);  // RNE (finite inputs)
  return (short)(u >> 16);
}
__device__ __forceinline__ float bf2f(short s) {
  return __uint_as_float(((unsigned)(unsigned short)s) << 16);
}

#define AS1 __attribute__((address_space(1)))
#define AS3 __attribute__((address_space(3)))

__device__ __forceinline__ void gload_lds16(const void* g, void* lds) {
  __builtin_amdgcn_global_load_lds((const AS1 void*)g, (AS3 void*)lds, 16, 0, 0);
}

// ---- W transpose+convert: Wt[n][k] = bf16(Wsrc[k][n]), 3 matrices ----------
__global__ void transpose_w(const float* __restrict__ W1,
                            const float* __restrict__ W2,
                            const float* __restrict__ Wl,
                            short* __restrict__ Wt) {
  __shared__ float t[32][33];
  const float* src = (blockIdx.z == 0) ? W1 : (blockIdx.z == 1) ? W2 : Wl;
  short* dst = Wt + (size_t)blockIdx.z * D * D;
  int tx = threadIdx.x, ty = threadIdx.y;
  t[ty][tx] = src[(size_t)(blockIdx.y * 32 + ty) * D + blockIdx.x * 32 + tx];
  __syncthreads();
  dst[(size_t)(blockIdx.x * 32 + ty) * D + blockIdx.y * 32 + tx] =
      f2bf(t[tx][ty]);
}

// ---- half-N strip GEMM: C[M, half] = A[M,256] @ Wt_half^T (+epilogue) ------
// Lesson of r1-r6: any design whose B lives in global memory loses — the
// compiler turns "resident B regs" into per-loop global traffic via remat
// (r1/r3), serialized pins (r4), or scratch spill (r6: FETCH 2.8x ideal).
// Here B's home is LDS: one 64KB XOR-swizzled half of Wt staged ONCE per
// block (pre-swizzled global_load_lds source, rule 21), one barrier total.
// bf[2][8] lifted LDS->regs; worst-case fallback is a cheap ds_read.
// A streams to regs with an explicit 2-deep pipeline (load(next) issued
// before compute(cur); two named frag sets, static indexing). 256 thr =
// 4 waves, wave w owns cols colBase + w*32..+31. launch_bounds(256,2) ->
// 256-VGPR budget, no spill; 64KB LDS -> 2 blocks/CU. Grid 512: block b
// and b+256 do the same strips, opposite col-half, same CU -> A re-read
// hits L1/L2 (FETCH stays ~ideal).
template <bool A_F32, bool ADD_ROW, bool FINAL>
__global__ __launch_bounds__(256, 2) void gemm_half(
    const void* __restrict__ Avoid, const short* __restrict__ Wt,
    const float* __restrict__ R, const int* __restrict__ batch,
    const float* __restrict__ bias, void* __restrict__ Cvoid, int M,
    int nStrips) {
  __shared__ __align__(16) short Bs[128 * 256];  // 64 KB, swizzled [n][k]
  const int tid = threadIdx.x;
  const int l = tid & 63, w = tid >> 6, lm = l & 15, q = l >> 4;
  const int half = gridDim.x >> 1;               // blocks per col-half
  const int nhalf = blockIdx.x / half;           // 0 or 1
  const int colBase = nhalf * 128;
  const int ncol0 = colBase + w * 32;            // wave's global col base

  // ---- stage B half [128 n][256 k] once; LDS slot s of row n holds global
  //      16B-slot s^(n&7) (XOR swizzle applied on the SOURCE address) ----
  {
    const short* Wh = Wt + (size_t)colBase * D;
#pragma unroll
    for (int r = 0; r < 16; r++) {
      const int c = w * 16 + r;        // 1KB-call id 0..63, wave-uniform
      const int n = 2 * c + (l >> 5);  // local col row 0..127
      const int slot = (l & 31) ^ (n & 7);
      gload_lds16((const char*)(Wh + (size_t)n * D) + slot * 16,
                  (char*)Bs + c * 1024);
    }
  }
  __syncthreads();  // only barrier in the kernel

  // ---- lift B fragments to regs (swizzled read: 2-way conflict = free) ----
  short8 bf[2][8];
#pragma unroll
  for (int j = 0; j < 2; j++)
#pragma unroll
    for (int kk = 0; kk < 8; kk++) {
      const int n = w * 32 + j * 16 + lm;
      const int slot = (kk * 4 + q) ^ (lm & 7);
      bf[j][kk] = *(const short8*)((const char*)Bs + n * 512 + slot * 16);
    }

  auto loadA = [&](short8(&a)[8], int sp) {
    int rl = sp * 16 + lm;
    rl = rl < M ? rl : M - 1;  // clamp (stores guarded)
    if (A_F32) {
      const float* ap = (const float*)Avoid + (size_t)rl * D + q * 8;
#pragma unroll
      for (int kk = 0; kk < 8; kk++) {
        float4 v0 = *(const float4*)(ap + (size_t)kk * 32);
        float4 v1 = *(const float4*)(ap + (size_t)kk * 32 + 4);
        short8 sv;
        sv[0] = f2bf(v0.x); sv[1] = f2bf(v0.y); sv[2] = f2bf(v0.z); sv[3] = f2bf(v0.w);
        sv[4] = f2bf(v1.x); sv[5] = f2bf(v1.y); sv[6] = f2bf(v1.z); sv[7] = f2bf(v1.w);
        a[kk] = sv;
      }
    } else {
      const short* ap = (const short*)Avoid + (size_t)rl * D + q * 8;
#pragma unroll
      for (int kk = 0; kk < 8; kk++)
        a[kk] = *(const short8*)(ap + (size_t)kk * 32);
    }
  };

  auto compute = [&](const short8(&a)[8], int sp) {
    floatx4 acc[2];
    acc[0] = (floatx4){0.f, 0.f, 0.f, 0.f};
    acc[1] = (floatx4){0.f, 0.f, 0.f, 0.f};
#pragma unroll
    for (int kk = 0; kk < 8; kk++)
#pragma unroll
      for (int j = 0; j < 2; j++)
        acc[j] = __builtin_amdgcn_mfma_f32_16x16x32_bf16(bf[j][kk], a[kk],
                                                         acc[j], 0, 0, 0);
    const int row = sp * 16 + lm;
    if (row < M) {
      int rb = 0;
      if (ADD_ROW) rb = batch[row];
#pragma unroll
      for (int j = 0; j < 2; j++) {
        const int col0 = ncol0 + j * 16 + q * 4;
        float c0 = acc[j][0], c1 = acc[j][1], c2 = acc[j][2], c3 = acc[j][3];
        if (ADD_ROW) {
          float4 rv = *(const float4*)(R + (size_t)rb * D + col0);
          c0 += rv.x; c1 += rv.y; c2 += rv.z; c3 += rv.w;
        }
        if (!FINAL) {
          uint2 o;
          o.x = (unsigned)(unsigned short)f2bf(c0) |
                ((unsigned)(unsigned short)f2bf(c1) << 16);
          o.y = (unsigned)(unsigned short)f2bf(c2) |
                ((unsigned)(unsigned short)f2bf(c3) << 16);
          *(uint2*)((short*)Cvoid + (size_t)row * D + col0) = o;
        } else {
          float4 bv = *(const float4*)(bias + col0);
          c0 += bv.x; c1 += bv.y; c2 += bv.z; c3 += bv.w;
          c0 = LEAKY(c0); c1 = LEAKY(c1); c2 = LEAKY(c2); c3 = LEAKY(c3);
          float4 o = {c0, c1, c2, c3};
          *(float4*)((float*)Cvoid + (size_t)row * D + col0) = o;
        }
      }
    }
  };

  // ---- 2-deep pipelined strip loop: load(next) in flight over compute(cur)
  const int stride = half;
  int sp = blockIdx.x % half;
  if (sp >= nStrips) return;
  short8 a0[8], a1[8];
  loadA(a0, sp);
  while (true) {
    int spn = sp + stride;
    if (spn >= nStrips) { compute(a0, sp); break; }
    loadA(a1, spn);
    compute(a0, sp);
    sp = spn;
    spn = sp + stride;
    if (spn >= nStrips) { compute(a1, sp); break; }
    loadA(a0, spn);
    compute(a1, sp);
    sp = spn;
  }
}

// ---------------- CSR build --------------------------------------------------
__global__ void count_dst(const int* __restrict__ dst, int* __restrict__ offs,
                          int E) {
  int e = blockIdx.x * 256 + threadIdx.x;
  if (e < E) atomicAdd(&offs[dst[e]], 1);
}

__global__ void scan_blocks(int* __restrict__ offs, int* __restrict__ bsums,
                            int n) {
  __shared__ int tmp[256];
  int i = blockIdx.x * 256 + threadIdx.x;
  int v = (i < n) ? offs[i] : 0;
  tmp[threadIdx.x] = v;
  __syncthreads();
  for (int off = 1; off < 256; off <<= 1) {
    int t = (threadIdx.x >= off) ? tmp[threadIdx.x - off] : 0;
    __syncthreads();
    tmp[threadIdx.x] += t;
    __syncthreads();
  }
  if (i < n) offs[i] = tmp[threadIdx.x] - v;
  if (threadIdx.x == 255) bsums[blockIdx.x] = tmp[255];
}

__global__ void scan_sums(int* __restrict__ bs, int nb) {
  __shared__ int tmp[1024];
  int v = (threadIdx.x < nb) ? bs[threadIdx.x] : 0;
  tmp[threadIdx.x] = v;
  __syncthreads();
  for (int off = 1; off < 1024; off <<= 1) {
    int t = (threadIdx.x >= off) ? tmp[threadIdx.x - off] : 0;
    __syncthreads();
    tmp[threadIdx.x] += t;
    __syncthreads();
  }
  if (threadIdx.x < nb) bs[threadIdx.x] = tmp[threadIdx.x] - v;
}

__global__ void add_offsets(int* __restrict__ offs, const int* __restrict__ bs,
                            int n, int* __restrict__ cursor) {
  int i = blockIdx.x * 256 + threadIdx.x;
  if (i < n) {
    int o = offs[i] + bs[blockIdx.x];
    offs[i] = o;
    cursor[i] = o;
  }
}

__global__ void fill_buckets(const int* __restrict__ src,
                             const int* __restrict__ dst,
                             const float* __restrict__ vals,
                             int* __restrict__ cursor, int* __restrict__ esrc,
                             float* __restrict__ ew, int E) {
  int e = blockIdx.x * 256 + threadIdx.x;
  if (e < E) {
    int p = atomicAdd(&cursor[dst[e]], 1);
    esrc[p] = src[e];
    ew[p] = vals[e];
  }
}

// ---- gather agg (bf16 in/out): out[n] = bf16(leaky(sum w*H[src] + bias)) ---
__global__ __launch_bounds__(256) void aggregate_bf(
    const short* __restrict__ H, const int* __restrict__ offs,
    const int* __restrict__ esrc, const float* __restrict__ ew,
    const float* __restrict__ bias, short* __restrict__ out, int N, int E) {
  int node = blockIdx.x * 4 + (threadIdx.x >> 6);
  if (node >= N) return;
  int lane = threadIdx.x & 63;
  int beg = offs[node];
  int end = (node == N - 1) ? E : offs[node + 1];
  float a0 = 0.f, a1 = 0.f, a2 = 0.f, a3 = 0.f;
  int i = beg;
  for (; i + 1 < end; i += 2) {
    int s0 = esrc[i], s1 = esrc[i + 1];
    float w0 = ew[i], w1 = ew[i + 1];
    uint2 p0 = ((const uint2*)(H + (size_t)s0 * D))[lane];
    uint2 p1 = ((const uint2*)(H + (size_t)s1 * D))[lane];
    a0 += w0 * bf2f((short)(p0.x & 0xffff)) + w1 * bf2f((short)(p1.x & 0xffff));
    a1 += w0 * bf2f((short)(p0.x >> 16))    + w1 * bf2f((short)(p1.x >> 16));
    a2 += w0 * bf2f((short)(p0.y & 0xffff)) + w1 * bf2f((short)(p1.y & 0xffff));
    a3 += w0 * bf2f((short)(p0.y >> 16))    + w1 * bf2f((short)(p1.y >> 16));
  }
  if (i < end) {
    int s = esrc[i];
    float wv = ew[i];
    uint2 pk = ((const uint2*)(H + (size_t)s * D))[lane];
    a0 += wv * bf2f((short)(pk.x & 0xffff));
    a1 += wv * bf2f((short)(pk.x >> 16));
    a2 += wv * bf2f((short)(pk.y & 0xffff));
    a3 += wv * bf2f((short)(pk.y >> 16));
  }
  float4 b = ((const float4*)bias)[lane];
  a0 = LEAKY(a0 + b.x);
  a1 = LEAKY(a1 + b.y);
  a2 = LEAKY(a2 + b.z);
  a3 = LEAKY(a3 + b.w);
  uint2 o;
  o.x = (unsigned)(unsigned short)f2bf(a0) |
        ((unsigned)(unsigned short)f2bf(a1) << 16);
  o.y = (unsigned)(unsigned short)f2bf(a2) |
        ((unsigned)(unsigned short)f2bf(a3) << 16);
  ((uint2*)(out + (size_t)node * D))[lane] = o;
}

// ---- R1[b,:] = leaky(features[root_b]) @ W2[256:512] (fp32) ----------------
__global__ void root_gemm1(const float* __restrict__ X,
                           const int* __restrict__ root_idx,
                           const float* __restrict__ W2,
                           float* __restrict__ R1) {
  __shared__ float a[D];
  int b = blockIdx.x, j = threadIdx.x;
  int r = root_idx[b];
  a[j] = LEAKY(X[(size_t)r * D + j]);
  __syncthreads();
  float acc = 0.f;
#pragma unroll 8
  for (int k = 0; k < D; k++) acc += a[k] * W2[(size_t)(D + k) * D + j];
  R1[b * D + j] = acc;
}

// ---- R2[b,:] = (agg1[root_b]+b1) @ Wl[256:512]  (recompute agg for root) ---
__global__ void root_gemm2(const short* __restrict__ H,
                           const int* __restrict__ root_idx,
                           const int* __restrict__ offs,
                           const int* __restrict__ esrc,
                           const float* __restrict__ ew,
                           const float* __restrict__ b1,
                           const float* __restrict__ Wl, float* __restrict__ R2,
                           int N, int E) {
  __shared__ float a[D];
  int b = blockIdx.x, j = threadIdx.x;
  int r = root_idx[b];
  int beg = offs[r], end = (r == N - 1) ? E : offs[r + 1];
  float acc = b1[j];
  for (int e = beg; e < end; e++)
    acc += ew[e] * bf2f(H[(size_t)esrc[e] * D + j]);
  a[j] = acc;
  __syncthreads();
  float s = 0.f;
#pragma unroll 8
  for (int k = 0; k < D; k++) s += a[k] * Wl[(size_t)(D + k) * D + j];
  R2[b * D + j] = s;
}

extern "C" void kernel_launch(void* const* d_in, const int* in_sizes, int n_in,
                              void* d_out, int out_size, void* d_ws,
                              size_t ws_size, hipStream_t stream) {
  const float* features = (const float*)d_in[0];  // [N,256]
  const float* values   = (const float*)d_in[1];  // [E]
  const float* W1 = (const float*)d_in[2];        // [256,256]
  const float* b1 = (const float*)d_in[3];        // [256]
  const float* W2 = (const float*)d_in[4];        // [512,256]
  const float* b2 = (const float*)d_in[5];        // [256]
  const float* Wl = (const float*)d_in[6];        // [512,256]
  const float* bl = (const float*)d_in[7];        // [256]
  const int* adjs = (const int*)d_in[8];          // [2,E]
  const int* batch = (const int*)d_in[9];         // [N]
  const int* root_idx = (const int*)d_in[10];     // [B]

  const int N = in_sizes[0] / D;
  const int E = in_sizes[1];
  const int B = in_sizes[10];
  const int* srcI = adjs;
  const int* dstI = adjs + E;

  // workspace layout
  short* bf0 = (short*)d_ws;            // h0_bf, then h2_bf   [N*256]
  short* bf1 = bf0 + (size_t)N * D;     // a1_bf, then a2_bf   [N*256]
  short* Wt = bf1 + (size_t)N * D;      // 3 x [256,256] bf16 (n-major)
  float* R1 = (float*)(Wt + (size_t)3 * D * D);  // [B,256]
  float* R2 = R1 + (size_t)B * D;                // [B,256]
  float* ew = R2 + (size_t)B * D;                // [E]
  int* offs = (int*)(ew + E);                    // [N]
  int* cursor = offs + N;                        // [N]
  int* esrc = cursor + N;                        // [E]
  int* bsums = esrc + E;                         // [<=1024]

  const int nb = (N + 255) / 256;  // 391 <= 1024

  // ---- build dst-CSR (reused by both aggregations + root2) ----
  hipMemsetAsync(offs, 0, (size_t)N * sizeof(int), stream);
  count_dst<<<(E + 255) / 256, 256, 0, stream>>>(dstI, offs, E);
  scan_blocks<<<nb, 256, 0, stream>>>(offs, bsums, N);
  scan_sums<<<1, 1024, 0, stream>>>(bsums, nb);
  add_offsets<<<nb, 256, 0, stream>>>(offs, bsums, N, cursor);
  fill_buckets<<<(E + 255) / 256, 256, 0, stream>>>(srcI, dstI, values, cursor,
                                                    esrc, ew, E);

  // ---- weights -> bf16, transposed to [n][k] ----
  transpose_w<<<dim3(8, 8, 3), dim3(32, 32), 0, stream>>>(W1, W2, Wl, Wt);

  const int nStrips = (N + 15) / 16;  // 6250
  const int ggrid = 512;              // 2 col-halves x 256; 2 blocks/CU
  const int aggGrid = (N + 3) / 4;

  // 1) h0 = features @ W1           (fp32 in fused-convert, bf16 out)
  gemm_half<true, false, false><<<ggrid, 256, 0, stream>>>(
      features, Wt, nullptr, nullptr, nullptr, bf0, N, nStrips);

  // 2) a1 = leaky(segsum(w*h0) + b1)  (bf16)
  aggregate_bf<<<aggGrid, 256, 0, stream>>>(bf0, offs, esrc, ew, b1, bf1, N, E);

  // 3) R1, R2 (root2 recomputes pre-leaky agg1 rows from CSR)
  root_gemm1<<<B, 256, 0, stream>>>(features, root_idx, W2, R1);
  root_gemm2<<<B, 256, 0, stream>>>(bf0, root_idx, offs, esrc, ew, b1, Wl, R2,
                                    N, E);

  // 4) h2 = a1 @ W2_top + R1[batch]   (bf16 in/out; overwrites h0 after root2)
  gemm_half<false, true, false><<<ggrid, 256, 0, stream>>>(
      bf1, Wt + (size_t)D * D, R1, batch, nullptr, bf0, N, nStrips);

  // 5) a2 = leaky(segsum(w*h2) + b2)  (bf16)
  aggregate_bf<<<aggGrid, 256, 0, stream>>>(bf0, offs, esrc, ew, b2, bf1, N, E);

  // 6) out = leaky(a2 @ Wl_top + R2[batch] + bl)  (fp32 out)
  gemm_half<false, true, true><<<ggrid, 256, 0, stream>>>(
      bf1, Wt + (size_t)2 * D * D, R2, batch, bl, (float*)d_out, N, nStrips);
}

// Round 8
// 434.223 us; speedup vs baseline: 1.3021x; 1.2346x over previous
//
#include <hip/hip_runtime.h>

typedef short short8 __attribute__((ext_vector_type(8)));
typedef float floatx4 __attribute__((ext_vector_type(4)));

#define LEAKY(v) ((v) >= 0.0f ? (v) : 0.01f * (v))

constexpr int D = 256;  // in = hid = out = 256

__device__ __forceinline__ short f2bf(float x) {
  unsigned u = __float_as_uint(x);
  u += 0x7fffu + ((u >> 16) & 1u);  // RNE (finite inputs)
  return (short)(u >> 16);
}
__device__ __forceinline__ float bf2f(short s) {
  return __uint_as_float(((unsigned)(unsigned short)s) << 16);
}

#define AS1 __attribute__((address_space(1)))
#define AS3 __attribute__((address_space(3)))

__device__ __forceinline__ void gload_lds16(const void* g, void* lds) {
  __builtin_amdgcn_global_load_lds((const AS1 void*)g, (AS3 void*)lds, 16, 0, 0);
}

// ---- W transpose+convert: Wt[n][k] = bf16(Wsrc[k][n]), 3 matrices ----------
__global__ void transpose_w(const float* __restrict__ W1,
                            const float* __restrict__ W2,
                            const float* __restrict__ Wl,
                            short* __restrict__ Wt) {
  __shared__ float t[32][33];
  const float* src = (blockIdx.z == 0) ? W1 : (blockIdx.z == 1) ? W2 : Wl;
  short* dst = Wt + (size_t)blockIdx.z * D * D;
  int tx = threadIdx.x, ty = threadIdx.y;
  t[ty][tx] = src[(size_t)(blockIdx.y * 32 + ty) * D + blockIdx.x * 32 + tx];
  __syncthreads();
  dst[(size_t)(blockIdx.x * 32 + ty) * D + blockIdx.y * 32 + tx] =
      f2bf(t[tx][ty]);
}

// ---- f32 -> bf16 convert (vectorized, grid-stride) -------------------------
__global__ __launch_bounds__(256) void conv_bf(const float* __restrict__ X,
                                               short* __restrict__ Y,
                                               long n8) {
  long i = (long)blockIdx.x * 256 + threadIdx.x;  // unit: 8 elements
  const long stride = (long)gridDim.x * 256;
  for (; i < n8; i += stride) {
    float4 v0 = ((const float4*)X)[2 * i];
    float4 v1 = ((const float4*)X)[2 * i + 1];
    short8 s;
    s[0] = f2bf(v0.x); s[1] = f2bf(v0.y); s[2] = f2bf(v0.z); s[3] = f2bf(v0.w);
    s[4] = f2bf(v1.x); s[5] = f2bf(v1.y); s[6] = f2bf(v1.z); s[7] = f2bf(v1.w);
    ((short8*)Y)[i] = s;
  }
}

// ---- persistent dbuf MFMA GEMM, BM=32: C[M,256]=A[M,256]@Wt^T --------------
// r5 structure (best measured: ~55us) with ONE change: BM 64->32 so LDS is
// 2x16KB=32KB -> grid 512 = 2 blocks/CU. While one block sits in its
// __syncthreads vmcnt(0) drain (the r5 serial term: at 1 block/CU the whole
// CU idled there), the co-resident block computes. Everything else is the
// proven r5 machinery: fragment-ordered global_load_lds (0 bank conflicts,
// slot s=kk*2+i holds the 1KB consumed as a[i] at k-block kk; wave-uniform
// dst + lane*16), B frags loaded then pinned AFTER all issues (r5 idiom:
// remat illegal past volatile asm, one latency; r4 proved per-load pins
// serialize; r6 proved a 128-cap with BM=64 spills -- BM=32 budget:
// bf 64 + acc 16 + a 16 + addr ~ 120 <= 128, no spill).
template <bool ADD_ROW, bool FINAL>
__global__ __launch_bounds__(512, 2) void gemm_pipe(
    const short* __restrict__ A, const short* __restrict__ Wt,
    const float* __restrict__ R, const int* __restrict__ batch,
    const float* __restrict__ bias, void* __restrict__ Cvoid, int M,
    int nTiles) {
  __shared__ __align__(16) short As[2][32 * 256];  // 2 x 16 KB
  const int tid = threadIdx.x;
  const int l = tid & 63, w = tid >> 6, lm = l & 15, q = l >> 4;
  const int ncol0 = w * 32;

  // resident B fragments: 2 n-frags x 8 k-frags -> 64 VGPR
  short8 bf[2][8];
#pragma unroll
  for (int j = 0; j < 2; j++)
#pragma unroll
    for (int kk = 0; kk < 8; kk++)
      bf[j][kk] = *(const short8*)(Wt + (size_t)(ncol0 + j * 16 + lm) * D +
                                   kk * 32 + q * 8);
#pragma unroll
  for (int j = 0; j < 2; j++)
#pragma unroll
    for (int kk = 0; kk < 8; kk++)
      asm volatile("" : "+v"(bf[j][kk]));  // pin AFTER all loads issued

  float4 b4[2];
  if (FINAL) {
#pragma unroll
    for (int j = 0; j < 2; j++)
      b4[j] = *(const float4*)(bias + ncol0 + j * 16 + q * 4);
  }

  const int stride = gridDim.x;
  int t = blockIdx.x;
  int p = 0;

  auto stage = [&](int tile, int buf) {
#pragma unroll
    for (int r = 0; r < 2; r++) {
      const int s = r * 8 + w;           // slot 0..15, wave-uniform
      const int kk = s >> 1, i = s & 1;  // fragment (kk, i)
      int grow = tile * 32 + i * 16 + lm;
      grow = grow < M ? grow : M - 1;  // clamp tail (stores guarded)
      const char* src = (const char*)A + (size_t)grow * 512 + kk * 64 + q * 16;
      gload_lds16(src, (char*)(&As[buf][0]) + s * 1024);
    }
  };

  if (t < nTiles) stage(t, 0);

  for (; t < nTiles; t += stride) {
    __syncthreads();  // drains vmcnt: stage(t) landed; buf p^1 released
    const int nxt = t + stride;
    if (nxt < nTiles) stage(nxt, p ^ 1);  // DMA overlaps compute below

    floatx4 acc[2][2];
#pragma unroll
    for (int i = 0; i < 2; i++)
#pragma unroll
      for (int j = 0; j < 2; j++) acc[i][j] = (floatx4){0.f, 0.f, 0.f, 0.f};

    const char* base = (const char*)(&As[p][0]) + (size_t)l * 16;
#pragma unroll
    for (int kk = 0; kk < 8; kk++) {
      short8 a[2];
#pragma unroll
      for (int i = 0; i < 2; i++)
        a[i] = *(const short8*)(base + (kk * 2 + i) * 1024);
#pragma unroll
      for (int i = 0; i < 2; i++)
#pragma unroll
        for (int j = 0; j < 2; j++)
          acc[i][j] = __builtin_amdgcn_mfma_f32_16x16x32_bf16(
              bf[j][kk], a[i], acc[i][j], 0, 0, 0);
    }

    // epilogue: lane holds rows i*16+lm, cols ncol0+j*16+q*4 .. +3
    const int rowBase = t * 32;
#pragma unroll
    for (int i = 0; i < 2; i++) {
      const int row = rowBase + i * 16 + lm;
      if (row < M) {
        int rb = 0;
        if (ADD_ROW) rb = batch[row];
#pragma unroll
        for (int j = 0; j < 2; j++) {
          const int col0 = ncol0 + j * 16 + q * 4;
          float c0 = acc[i][j][0], c1 = acc[i][j][1], c2 = acc[i][j][2],
                c3 = acc[i][j][3];
          if (ADD_ROW) {
            float4 rv = *(const float4*)(R + (size_t)rb * D + col0);
            c0 += rv.x; c1 += rv.y; c2 += rv.z; c3 += rv.w;
          }
          if (!FINAL) {
            uint2 o;
            o.x = (unsigned)(unsigned short)f2bf(c0) |
                  ((unsigned)(unsigned short)f2bf(c1) << 16);
            o.y = (unsigned)(unsigned short)f2bf(c2) |
                  ((unsigned)(unsigned short)f2bf(c3) << 16);
            *(uint2*)((short*)Cvoid + (size_t)row * D + col0) = o;
          } else {
            c0 += b4[j].x; c1 += b4[j].y; c2 += b4[j].z; c3 += b4[j].w;
            c0 = LEAKY(c0); c1 = LEAKY(c1); c2 = LEAKY(c2); c3 = LEAKY(c3);
            float4 o = {c0, c1, c2, c3};
            *(float4*)((float*)Cvoid + (size_t)row * D + col0) = o;
          }
        }
      }
    }
    p ^= 1;
  }
}

// ---------------- CSR build --------------------------------------------------
__global__ void count_dst(const int* __restrict__ dst, int* __restrict__ offs,
                          int E) {
  int e = blockIdx.x * 256 + threadIdx.x;
  if (e < E) atomicAdd(&offs[dst[e]], 1);
}

__global__ void scan_blocks(int* __restrict__ offs, int* __restrict__ bsums,
                            int n) {
  __shared__ int tmp[256];
  int i = blockIdx.x * 256 + threadIdx.x;
  int v = (i < n) ? offs[i] : 0;
  tmp[threadIdx.x] = v;
  __syncthreads();
  for (int off = 1; off < 256; off <<= 1) {
    int t = (threadIdx.x >= off) ? tmp[threadIdx.x - off] : 0;
    __syncthreads();
    tmp[threadIdx.x] += t;
    __syncthreads();
  }
  if (i < n) offs[i] = tmp[threadIdx.x] - v;
  if (threadIdx.x == 255) bsums[blockIdx.x] = tmp[255];
}

__global__ void scan_sums(int* __restrict__ bs, int nb) {
  __shared__ int tmp[1024];
  int v = (threadIdx.x < nb) ? bs[threadIdx.x] : 0;
  tmp[threadIdx.x] = v;
  __syncthreads();
  for (int off = 1; off < 1024; off <<= 1) {
    int t = (threadIdx.x >= off) ? tmp[threadIdx.x - off] : 0;
    __syncthreads();
    tmp[threadIdx.x] += t;
    __syncthreads();
  }
  if (threadIdx.x < nb) bs[threadIdx.x] = tmp[threadIdx.x] - v;
}

__global__ void add_offsets(int* __restrict__ offs, const int* __restrict__ bs,
                            int n, int* __restrict__ cursor) {
  int i = blockIdx.x * 256 + threadIdx.x;
  if (i < n) {
    int o = offs[i] + bs[blockIdx.x];
    offs[i] = o;
    cursor[i] = o;
  }
}

__global__ void fill_buckets(const int* __restrict__ src,
                             const int* __restrict__ dst,
                             const float* __restrict__ vals,
                             int* __restrict__ cursor, int* __restrict__ esrc,
                             float* __restrict__ ew, int E) {
  int e = blockIdx.x * 256 + threadIdx.x;
  if (e < E) {
    int p = atomicAdd(&cursor[dst[e]], 1);
    esrc[p] = src[e];
    ew[p] = vals[e];
  }
}

// ---- gather agg (bf16 in/out): out[n] = bf16(leaky(sum w*H[src] + bias)) ---
__global__ __launch_bounds__(256) void aggregate_bf(
    const short* __restrict__ H, const int* __restrict__ offs,
    const int* __restrict__ esrc, const float* __restrict__ ew,
    const float* __restrict__ bias, short* __restrict__ out, int N, int E) {
  int node = blockIdx.x * 4 + (threadIdx.x >> 6);
  if (node >= N) return;
  int lane = threadIdx.x & 63;
  int beg = offs[node];
  int end = (node == N - 1) ? E : offs[node + 1];
  float a0 = 0.f, a1 = 0.f, a2 = 0.f, a3 = 0.f;
  int i = beg;
  for (; i + 1 < end; i += 2) {
    int s0 = esrc[i], s1 = esrc[i + 1];
    float w0 = ew[i], w1 = ew[i + 1];
    uint2 p0 = ((const uint2*)(H + (size_t)s0 * D))[lane];
    uint2 p1 = ((const uint2*)(H + (size_t)s1 * D))[lane];
    a0 += w0 * bf2f((short)(p0.x & 0xffff)) + w1 * bf2f((short)(p1.x & 0xffff));
    a1 += w0 * bf2f((short)(p0.x >> 16))    + w1 * bf2f((short)(p1.x >> 16));
    a2 += w0 * bf2f((short)(p0.y & 0xffff)) + w1 * bf2f((short)(p1.y & 0xffff));
    a3 += w0 * bf2f((short)(p0.y >> 16))    + w1 * bf2f((short)(p1.y >> 16));
  }
  if (i < end) {
    int s = esrc[i];
    float wv = ew[i];
    uint2 pk = ((const uint2*)(H + (size_t)s * D))[lane];
    a0 += wv * bf2f((short)(pk.x & 0xffff));
    a1 += wv * bf2f((short)(pk.x >> 16));
    a2 += wv * bf2f((short)(pk.y & 0xffff));
    a3 += wv * bf2f((short)(pk.y >> 16));
  }
  float4 b = ((const float4*)bias)[lane];
  a0 = LEAKY(a0 + b.x);
  a1 = LEAKY(a1 + b.y);
  a2 = LEAKY(a2 + b.z);
  a3 = LEAKY(a3 + b.w);
  uint2 o;
  o.x = (unsigned)(unsigned short)f2bf(a0) |
        ((unsigned)(unsigned short)f2bf(a1) << 16);
  o.y = (unsigned)(unsigned short)f2bf(a2) |
        ((unsigned)(unsigned short)f2bf(a3) << 16);
  ((uint2*)(out + (size_t)node * D))[lane] = o;
}

// ---- fused root gemms: blocks [0,B) -> R1, [B,2B) -> R2 --------------------
// R1[b,:] = leaky(features[root_b]) @ W2[256:512]
// R2[b,:] = (agg1[root_b]+b1) @ Wl[256:512]  (recompute agg for root)
__global__ void root_both(const float* __restrict__ X,
                          const int* __restrict__ root_idx,
                          const float* __restrict__ W2, float* __restrict__ R1,
                          const short* __restrict__ H,
                          const int* __restrict__ offs,
                          const int* __restrict__ esrc,
                          const float* __restrict__ ew,
                          const float* __restrict__ b1,
                          const float* __restrict__ Wl, float* __restrict__ R2,
                          int N, int E, int B) {
  __shared__ float a[D];
  int j = threadIdx.x;
  if ((int)blockIdx.x < B) {
    int b = blockIdx.x;
    int r = root_idx[b];
    a[j] = LEAKY(X[(size_t)r * D + j]);
    __syncthreads();
    float acc = 0.f;
#pragma unroll 8
    for (int k = 0; k < D; k++) acc += a[k] * W2[(size_t)(D + k) * D + j];
    R1[b * D + j] = acc;
  } else {
    int b = blockIdx.x - B;
    int r = root_idx[b];
    int beg = offs[r], end = (r == N - 1) ? E : offs[r + 1];
    float acc = b1[j];
    for (int e = beg; e < end; e++)
      acc += ew[e] * bf2f(H[(size_t)esrc[e] * D + j]);
    a[j] = acc;
    __syncthreads();
    float s = 0.f;
#pragma unroll 8
    for (int k = 0; k < D; k++) s += a[k] * Wl[(size_t)(D + k) * D + j];
    R2[b * D + j] = s;
  }
}

extern "C" void kernel_launch(void* const* d_in, const int* in_sizes, int n_in,
                              void* d_out, int out_size, void* d_ws,
                              size_t ws_size, hipStream_t stream) {
  const float* features = (const float*)d_in[0];  // [N,256]
  const float* values   = (const float*)d_in[1];  // [E]
  const float* W1 = (const float*)d_in[2];        // [256,256]
  const float* b1 = (const float*)d_in[3];        // [256]
  const float* W2 = (const float*)d_in[4];        // [512,256]
  const float* b2 = (const float*)d_in[5];        // [256]
  const float* Wl = (const float*)d_in[6];        // [512,256]
  const float* bl = (const float*)d_in[7];        // [256]
  const int* adjs = (const int*)d_in[8];          // [2,E]
  const int* batch = (const int*)d_in[9];         // [N]
  const int* root_idx = (const int*)d_in[10];     // [B]

  const int N = in_sizes[0] / D;
  const int E = in_sizes[1];
  const int B = in_sizes[10];
  const int* srcI = adjs;
  const int* dstI = adjs + E;

  // workspace layout
  short* bf0 = (short*)d_ws;            // h0_bf, then h2_bf   [N*256]
  short* bf1 = bf0 + (size_t)N * D;     // feat_bf, a1_bf, a2_bf [N*256]
  short* Wt = bf1 + (size_t)N * D;      // 3 x [256,256] bf16 (n-major)
  float* R1 = (float*)(Wt + (size_t)3 * D * D);  // [B,256]
  float* R2 = R1 + (size_t)B * D;                // [B,256]
  float* ew = R2 + (size_t)B * D;                // [E]
  int* offs = (int*)(ew + E);                    // [N]
  int* cursor = offs + N;                        // [N]
  int* esrc = cursor + N;                        // [E]
  int* bsums = esrc + E;                         // [<=1024]

  const int nb = (N + 255) / 256;  // 391 <= 1024

  // ---- build dst-CSR (reused by both aggregations + root2) ----
  hipMemsetAsync(offs, 0, (size_t)N * sizeof(int), stream);
  count_dst<<<(E + 255) / 256, 256, 0, stream>>>(dstI, offs, E);
  scan_blocks<<<nb, 256, 0, stream>>>(offs, bsums, N);
  scan_sums<<<1, 1024, 0, stream>>>(bsums, nb);
  add_offsets<<<nb, 256, 0, stream>>>(offs, bsums, N, cursor);
  fill_buckets<<<(E + 255) / 256, 256, 0, stream>>>(srcI, dstI, values, cursor,
                                                    esrc, ew, E);

  // ---- weights -> bf16, transposed to [n][k] ----
  transpose_w<<<dim3(8, 8, 3), dim3(32, 32), 0, stream>>>(W1, W2, Wl, Wt);

  // ---- features -> bf16 (into bf1; consumed by gemm1 before step 2) ----
  conv_bf<<<2048, 256, 0, stream>>>(features, bf1, (long)N * D / 8);

  const int nTiles = (N + 31) / 32;  // 3125
  const int ggrid = 512;             // persistent, 2 blocks/CU
  const int aggGrid = (N + 3) / 4;

  // 1) h0 = features @ W1           (bf16 in, bf16 out)
  gemm_pipe<false, false><<<ggrid, 512, 0, stream>>>(
      bf1, Wt, nullptr, nullptr, nullptr, bf0, N, nTiles);

  // 2) a1 = leaky(segsum(w*h0) + b1)  (bf16; overwrites feat_bf)
  aggregate_bf<<<aggGrid, 256, 0, stream>>>(bf0, offs, esrc, ew, b1, bf1, N, E);

  // 3) R1, R2 in one launch (root2 recomputes pre-leaky agg1 rows from CSR)
  root_both<<<2 * B, 256, 0, stream>>>(features, root_idx, W2, R1, bf0, offs,
                                       esrc, ew, b1, Wl, R2, N, E, B);

  // 4) h2 = a1 @ W2_top + R1[batch]   (bf16 in/out; overwrites h0 after root)
  gemm_pipe<true, false><<<ggrid, 512, 0, stream>>>(
      bf1, Wt + (size_t)D * D, R1, batch, nullptr, bf0, N, nTiles);

  // 5) a2 = leaky(segsum(w*h2) + b2)  (bf16)
  aggregate_bf<<<aggGrid, 256, 0, stream>>>(bf0, offs, esrc, ew, b2, bf1, N, E);

  // 6) out = leaky(a2 @ Wl_top + R2[batch] + bl)  (fp32 out)
  gemm_pipe<true, true><<<ggrid, 512, 0, stream>>>(
      bf1, Wt + (size_t)2 * D * D, R2, batch, bl, (float*)d_out, N, nTiles);
}

// Round 9
// 419.146 us; speedup vs baseline: 1.3489x; 1.0360x over previous
//
#include <hip/hip_runtime.h>

typedef short short8 __attribute__((ext_vector_type(8)));
typedef float floatx4 __attribute__((ext_vector_type(4)));

#define LEAKY(v) ((v) >= 0.0f ? (v) : 0.01f * (v))

constexpr int D = 256;  // in = hid = out = 256

__device__ __forceinline__ short f2bf(float x) {
  unsigned u = __float_as_uint(x);
  u += 0x7fffu + ((u >> 16) & 1u);  // RNE (finite inputs)
  return (short)(u >> 16);
}
__device__ __forceinline__ float bf2f(short s) {
  return __uint_as_float(((unsigned)(unsigned short)s) << 16);
}

#define AS1 __attribute__((address_space(1)))
#define AS3 __attribute__((address_space(3)))

__device__ __forceinline__ void gload_lds16(const void* g, void* lds) {
  __builtin_amdgcn_global_load_lds((const AS1 void*)g, (AS3 void*)lds, 16, 0, 0);
}

// ---- W transpose+convert: Wt[n][k] = bf16(Wsrc[k][n]), 3 matrices ----------
__global__ void transpose_w(const float* __restrict__ W1,
                            const float* __restrict__ W2,
                            const float* __restrict__ Wl,
                            short* __restrict__ Wt) {
  __shared__ float t[32][33];
  const float* src = (blockIdx.z == 0) ? W1 : (blockIdx.z == 1) ? W2 : Wl;
  short* dst = Wt + (size_t)blockIdx.z * D * D;
  int tx = threadIdx.x, ty = threadIdx.y;
  t[ty][tx] = src[(size_t)(blockIdx.y * 32 + ty) * D + blockIdx.x * 32 + tx];
  __syncthreads();
  dst[(size_t)(blockIdx.x * 32 + ty) * D + blockIdx.y * 32 + tx] =
      f2bf(t[tx][ty]);
}

// ---- persistent dbuf MFMA GEMM, BM=32 (r8 structure, best: 434us wall) -----
// 2 blocks/CU so the co-resident block covers each __syncthreads vmcnt drain
// (r8's proven win). Fragment-ordered global_load_lds (0 bank conflicts),
// B frags pinned AFTER all 16 loads issued (r5 idiom). NEW (r9): A_F32
// variant stages RAW f32 tiles (2x32KB LDS, slot=2KB: [half0 64x16B][half1
// 64x16B], both lane-linear) and converts to bf16 transiently at frag-read
// -- fuses conv_bf's 153MB pass into gemm1 (conversion VALU ~8us machine-
// wide, hidden under MFMA). LDS 128KB/CU still = 2 blocks/CU.
template <bool A_F32, bool ADD_ROW, bool FINAL>
__global__ __launch_bounds__(512, 2) void gemm_pipe(
    const void* __restrict__ Avoid, const short* __restrict__ Wt,
    const float* __restrict__ R, const int* __restrict__ batch,
    const float* __restrict__ bias, void* __restrict__ Cvoid, int M,
    int nTiles) {
  constexpr int TB = A_F32 ? 32768 : 16384;  // bytes per tile buffer
  __shared__ __align__(16) char As[2][TB];
  const int tid = threadIdx.x;
  const int l = tid & 63, w = tid >> 6, lm = l & 15, q = l >> 4;
  const int ncol0 = w * 32;

  // resident B fragments: 2 n-frags x 8 k-frags -> 64 VGPR
  short8 bf[2][8];
#pragma unroll
  for (int j = 0; j < 2; j++)
#pragma unroll
    for (int kk = 0; kk < 8; kk++)
      bf[j][kk] = *(const short8*)(Wt + (size_t)(ncol0 + j * 16 + lm) * D +
                                   kk * 32 + q * 8);
#pragma unroll
  for (int j = 0; j < 2; j++)
#pragma unroll
    for (int kk = 0; kk < 8; kk++)
      asm volatile("" : "+v"(bf[j][kk]));  // pin AFTER all loads issued

  float4 b4[2];
  if (FINAL) {
#pragma unroll
    for (int j = 0; j < 2; j++)
      b4[j] = *(const float4*)(bias + ncol0 + j * 16 + q * 4);
  }

  const int stride = gridDim.x;
  int t = blockIdx.x;
  int p = 0;

  auto stage = [&](int tile, int buf) {
    if (A_F32) {
      // 32 wave-calls: slot s (kk,i) half h; lane l's 16B (4 floats) ->
      // slot*2048 + h*1024 + l*16 (implicit lane offset)
#pragma unroll
      for (int r = 0; r < 4; r++) {
        const int c = r * 8 + w;            // 0..31, wave-uniform
        const int s = c >> 1, h = c & 1;    // slot, half
        const int kk = s >> 1, i = s & 1;   // fragment (kk, i)
        int grow = tile * 32 + i * 16 + lm;
        grow = grow < M ? grow : M - 1;  // clamp tail (stores guarded)
        const char* src = (const char*)Avoid + (size_t)grow * 1024 +
                          kk * 128 + q * 32 + h * 16;
        gload_lds16(src, &As[buf][s * 2048 + h * 1024]);
      }
    } else {
#pragma unroll
      for (int r = 0; r < 2; r++) {
        const int s = r * 8 + w;           // slot 0..15, wave-uniform
        const int kk = s >> 1, i = s & 1;  // fragment (kk, i)
        int grow = tile * 32 + i * 16 + lm;
        grow = grow < M ? grow : M - 1;
        const char* src =
            (const char*)Avoid + (size_t)grow * 512 + kk * 64 + q * 16;
        gload_lds16(src, &As[buf][s * 1024]);
      }
    }
  };

  if (t < nTiles) stage(t, 0);

  for (; t < nTiles; t += stride) {
    __syncthreads();  // drains vmcnt: stage(t) landed; buf p^1 released
    const int nxt = t + stride;
    if (nxt < nTiles) stage(nxt, p ^ 1);  // DMA overlaps compute below

    floatx4 acc[2][2];
#pragma unroll
    for (int i = 0; i < 2; i++)
#pragma unroll
      for (int j = 0; j < 2; j++) acc[i][j] = (floatx4){0.f, 0.f, 0.f, 0.f};

    const char* base = &As[p][0] + (size_t)l * 16;
#pragma unroll
    for (int kk = 0; kk < 8; kk++) {
      short8 a[2];
#pragma unroll
      for (int i = 0; i < 2; i++) {
        if (A_F32) {
          const int s = kk * 2 + i;
          float4 lo = *(const float4*)(base + s * 2048);
          float4 hi = *(const float4*)(base + s * 2048 + 1024);
          short8 sv;
          sv[0] = f2bf(lo.x); sv[1] = f2bf(lo.y); sv[2] = f2bf(lo.z); sv[3] = f2bf(lo.w);
          sv[4] = f2bf(hi.x); sv[5] = f2bf(hi.y); sv[6] = f2bf(hi.z); sv[7] = f2bf(hi.w);
          a[i] = sv;
        } else {
          a[i] = *(const short8*)(base + (kk * 2 + i) * 1024);
        }
      }
#pragma unroll
      for (int i = 0; i < 2; i++)
#pragma unroll
        for (int j = 0; j < 2; j++)
          acc[i][j] = __builtin_amdgcn_mfma_f32_16x16x32_bf16(
              bf[j][kk], a[i], acc[i][j], 0, 0, 0);
    }

    // epilogue: lane holds rows i*16+lm, cols ncol0+j*16+q*4 .. +3
    const int rowBase = t * 32;
#pragma unroll
    for (int i = 0; i < 2; i++) {
      const int row = rowBase + i * 16 + lm;
      if (row < M) {
        int rb = 0;
        if (ADD_ROW) rb = batch[row];
#pragma unroll
        for (int j = 0; j < 2; j++) {
          const int col0 = ncol0 + j * 16 + q * 4;
          float c0 = acc[i][j][0], c1 = acc[i][j][1], c2 = acc[i][j][2],
                c3 = acc[i][j][3];
          if (ADD_ROW) {
            float4 rv = *(const float4*)(R + (size_t)rb * D + col0);
            c0 += rv.x; c1 += rv.y; c2 += rv.z; c3 += rv.w;
          }
          if (!FINAL) {
            uint2 o;
            o.x = (unsigned)(unsigned short)f2bf(c0) |
                  ((unsigned)(unsigned short)f2bf(c1) << 16);
            o.y = (unsigned)(unsigned short)f2bf(c2) |
                  ((unsigned)(unsigned short)f2bf(c3) << 16);
            *(uint2*)((short*)Cvoid + (size_t)row * D + col0) = o;
          } else {
            c0 += b4[j].x; c1 += b4[j].y; c2 += b4[j].z; c3 += b4[j].w;
            c0 = LEAKY(c0); c1 = LEAKY(c1); c2 = LEAKY(c2); c3 = LEAKY(c3);
            float4 o = {c0, c1, c2, c3};
            *(float4*)((float*)Cvoid + (size_t)row * D + col0) = o;
          }
        }
      }
    }
    p ^= 1;
  }
}

// ---------------- CSR build --------------------------------------------------
__global__ void count_dst(const int* __restrict__ dst, int* __restrict__ offs,
                          int E) {
  int e = blockIdx.x * 256 + threadIdx.x;
  if (e < E) atomicAdd(&offs[dst[e]], 1);
}

__global__ void scan_blocks(int* __restrict__ offs, int* __restrict__ bsums,
                            int n) {
  __shared__ int tmp[256];
  int i = blockIdx.x * 256 + threadIdx.x;
  int v = (i < n) ? offs[i] : 0;
  tmp[threadIdx.x] = v;
  __syncthreads();
  for (int off = 1; off < 256; off <<= 1) {
    int t = (threadIdx.x >= off) ? tmp[threadIdx.x - off] : 0;
    __syncthreads();
    tmp[threadIdx.x] += t;
    __syncthreads();
  }
  if (i < n) offs[i] = tmp[threadIdx.x] - v;
  if (threadIdx.x == 255) bsums[blockIdx.x] = tmp[255];
}

__global__ void scan_sums(int* __restrict__ bs, int nb) {
  __shared__ int tmp[1024];
  int v = (threadIdx.x < nb) ? bs[threadIdx.x] : 0;
  tmp[threadIdx.x] = v;
  __syncthreads();
  for (int off = 1; off < 1024; off <<= 1) {
    int t = (threadIdx.x >= off) ? tmp[threadIdx.x - off] : 0;
    __syncthreads();
    tmp[threadIdx.x] += t;
    __syncthreads();
  }
  if (threadIdx.x < nb) bs[threadIdx.x] = tmp[threadIdx.x] - v;
}

__global__ void add_offsets(int* __restrict__ offs, const int* __restrict__ bs,
                            int n, int* __restrict__ cursor) {
  int i = blockIdx.x * 256 + threadIdx.x;
  if (i < n) {
    int o = offs[i] + bs[blockIdx.x];
    offs[i] = o;
    cursor[i] = o;
  }
}

__global__ void fill_buckets(const int* __restrict__ src,
                             const int* __restrict__ dst,
                             const float* __restrict__ vals,
                             int* __restrict__ cursor, int* __restrict__ esrc,
                             float* __restrict__ ew, int E) {
  int e = blockIdx.x * 256 + threadIdx.x;
  if (e < E) {
    int p = atomicAdd(&cursor[dst[e]], 1);
    esrc[p] = src[e];
    ew[p] = vals[e];
  }
}

// ---- gather agg, 2 edges/wave: out[n] = bf16(leaky(sum w*H[src] + bias)) ---
// 32-lane halves each read a FULL 512B row as uint4 (16B/lane): two
// independent gathers in flight per iteration, half the instructions of the
// old one-edge/uint2 loop. Halves combined with one shfl_xor(32) per acc.
__global__ __launch_bounds__(256) void aggregate_bf(
    const short* __restrict__ H, const int* __restrict__ offs,
    const int* __restrict__ esrc, const float* __restrict__ ew,
    const float* __restrict__ bias, short* __restrict__ out, int N, int E) {
  int node = blockIdx.x * 4 + (threadIdx.x >> 6);
  if (node >= N) return;
  const int lane = threadIdx.x & 63;
  const int half = lane >> 5, li = lane & 31;
  int beg = offs[node];
  int end = (node == N - 1) ? E : offs[node + 1];
  float a0 = 0.f, a1 = 0.f, a2 = 0.f, a3 = 0.f, a4 = 0.f, a5 = 0.f,
        a6 = 0.f, a7 = 0.f;
  for (int i = beg; i < end; i += 2) {
    const int idx = i + half;
    const bool v = idx < end;
    int s = esrc[v ? idx : i];
    float wv = v ? ew[idx] : 0.f;
    uint4 pk = *(const uint4*)(H + (size_t)s * D + li * 8);  // 8 bf16
    a0 += wv * bf2f((short)(pk.x & 0xffff));
    a1 += wv * bf2f((short)(pk.x >> 16));
    a2 += wv * bf2f((short)(pk.y & 0xffff));
    a3 += wv * bf2f((short)(pk.y >> 16));
    a4 += wv * bf2f((short)(pk.z & 0xffff));
    a5 += wv * bf2f((short)(pk.z >> 16));
    a6 += wv * bf2f((short)(pk.w & 0xffff));
    a7 += wv * bf2f((short)(pk.w >> 16));
  }
  // combine the two 32-lane halves (lane l <-> l+32)
  a0 += __shfl_xor(a0, 32); a1 += __shfl_xor(a1, 32);
  a2 += __shfl_xor(a2, 32); a3 += __shfl_xor(a3, 32);
  a4 += __shfl_xor(a4, 32); a5 += __shfl_xor(a5, 32);
  a6 += __shfl_xor(a6, 32); a7 += __shfl_xor(a7, 32);
  if (half == 0) {
    float4 b0 = *(const float4*)(bias + li * 8);
    float4 b1 = *(const float4*)(bias + li * 8 + 4);
    a0 = LEAKY(a0 + b0.x); a1 = LEAKY(a1 + b0.y);
    a2 = LEAKY(a2 + b0.z); a3 = LEAKY(a3 + b0.w);
    a4 = LEAKY(a4 + b1.x); a5 = LEAKY(a5 + b1.y);
    a6 = LEAKY(a6 + b1.z); a7 = LEAKY(a7 + b1.w);
    uint4 o;
    o.x = (unsigned)(unsigned short)f2bf(a0) |
          ((unsigned)(unsigned short)f2bf(a1) << 16);
    o.y = (unsigned)(unsigned short)f2bf(a2) |
          ((unsigned)(unsigned short)f2bf(a3) << 16);
    o.z = (unsigned)(unsigned short)f2bf(a4) |
          ((unsigned)(unsigned short)f2bf(a5) << 16);
    o.w = (unsigned)(unsigned short)f2bf(a6) |
          ((unsigned)(unsigned short)f2bf(a7) << 16);
    *(uint4*)(out + (size_t)node * D + li * 8) = o;
  }
}

// ---- fused root gemms: blocks [0,B) -> R1, [B,2B) -> R2 --------------------
__global__ void root_both(const float* __restrict__ X,
                          const int* __restrict__ root_idx,
                          const float* __restrict__ W2, float* __restrict__ R1,
                          const short* __restrict__ H,
                          const int* __restrict__ offs,
                          const int* __restrict__ esrc,
                          const float* __restrict__ ew,
                          const float* __restrict__ b1,
                          const float* __restrict__ Wl, float* __restrict__ R2,
                          int N, int E, int B) {
  __shared__ float a[D];
  int j = threadIdx.x;
  if ((int)blockIdx.x < B) {
    int b = blockIdx.x;
    int r = root_idx[b];
    a[j] = LEAKY(X[(size_t)r * D + j]);
    __syncthreads();
    float acc = 0.f;
#pragma unroll 8
    for (int k = 0; k < D; k++) acc += a[k] * W2[(size_t)(D + k) * D + j];
    R1[b * D + j] = acc;
  } else {
    int b = blockIdx.x - B;
    int r = root_idx[b];
    int beg = offs[r], end = (r == N - 1) ? E : offs[r + 1];
    float acc = b1[j];
    for (int e = beg; e < end; e++)
      acc += ew[e] * bf2f(H[(size_t)esrc[e] * D + j]);
    a[j] = acc;
    __syncthreads();
    float s = 0.f;
#pragma unroll 8
    for (int k = 0; k < D; k++) s += a[k] * Wl[(size_t)(D + k) * D + j];
    R2[b * D + j] = s;
  }
}

extern "C" void kernel_launch(void* const* d_in, const int* in_sizes, int n_in,
                              void* d_out, int out_size, void* d_ws,
                              size_t ws_size, hipStream_t stream) {
  const float* features = (const float*)d_in[0];  // [N,256]
  const float* values   = (const float*)d_in[1];  // [E]
  const float* W1 = (const float*)d_in[2];        // [256,256]
  const float* b1 = (const float*)d_in[3];        // [256]
  const float* W2 = (const float*)d_in[4];        // [512,256]
  const float* b2 = (const float*)d_in[5];        // [256]
  const float* Wl = (const float*)d_in[6];        // [512,256]
  const float* bl = (const float*)d_in[7];        // [256]
  const int* adjs = (const int*)d_in[8];          // [2,E]
  const int* batch = (const int*)d_in[9];         // [N]
  const int* root_idx = (const int*)d_in[10];     // [B]

  const int N = in_sizes[0] / D;
  const int E = in_sizes[1];
  const int B = in_sizes[10];
  const int* srcI = adjs;
  const int* dstI = adjs + E;

  // workspace layout
  short* bf0 = (short*)d_ws;            // h0_bf, then h2_bf   [N*256]
  short* bf1 = bf0 + (size_t)N * D;     // a1_bf, then a2_bf   [N*256]
  short* Wt = bf1 + (size_t)N * D;      // 3 x [256,256] bf16 (n-major)
  float* R1 = (float*)(Wt + (size_t)3 * D * D);  // [B,256]
  float* R2 = R1 + (size_t)B * D;                // [B,256]
  float* ew = R2 + (size_t)B * D;                // [E]
  int* offs = (int*)(ew + E);                    // [N]
  int* cursor = offs + N;                        // [N]
  int* esrc = cursor + N;                        // [E]
  int* bsums = esrc + E;                         // [<=1024]

  const int nb = (N + 255) / 256;  // 391 <= 1024

  // ---- build dst-CSR (reused by both aggregations + root2) ----
  hipMemsetAsync(offs, 0, (size_t)N * sizeof(int), stream);
  count_dst<<<(E + 255) / 256, 256, 0, stream>>>(dstI, offs, E);
  scan_blocks<<<nb, 256, 0, stream>>>(offs, bsums, N);
  scan_sums<<<1, 1024, 0, stream>>>(bsums, nb);
  add_offsets<<<nb, 256, 0, stream>>>(offs, bsums, N, cursor);
  fill_buckets<<<(E + 255) / 256, 256, 0, stream>>>(srcI, dstI, values, cursor,
                                                    esrc, ew, E);

  // ---- weights -> bf16, transposed to [n][k] ----
  transpose_w<<<dim3(8, 8, 3), dim3(32, 32), 0, stream>>>(W1, W2, Wl, Wt);

  const int nTiles = (N + 31) / 32;  // 3125
  const int ggrid = 512;             // persistent, 2 blocks/CU
  const int aggGrid = (N + 3) / 4;

  // 1) h0 = features @ W1           (fp32 in, fused convert, bf16 out)
  gemm_pipe<true, false, false><<<ggrid, 512, 0, stream>>>(
      features, Wt, nullptr, nullptr, nullptr, bf0, N, nTiles);

  // 2) a1 = leaky(segsum(w*h0) + b1)  (bf16)
  aggregate_bf<<<aggGrid, 256, 0, stream>>>(bf0, offs, esrc, ew, b1, bf1, N, E);

  // 3) R1, R2 in one launch (root2 recomputes pre-leaky agg1 rows from CSR)
  root_both<<<2 * B, 256, 0, stream>>>(features, root_idx, W2, R1, bf0, offs,
                                       esrc, ew, b1, Wl, R2, N, E, B);

  // 4) h2 = a1 @ W2_top + R1[batch]   (bf16 in/out; overwrites h0 after root)
  gemm_pipe<false, true, false><<<ggrid, 512, 0, stream>>>(
      bf1, Wt + (size_t)D * D, R1, batch, nullptr, bf0, N, nTiles);

  // 5) a2 = leaky(segsum(w*h2) + b2)  (bf16)
  aggregate_bf<<<aggGrid, 256, 0, stream>>>(bf0, offs, esrc, ew, b2, bf1, N, E);

  // 6) out = leaky(a2 @ Wl_top + R2[batch] + bl)  (fp32 out)
  gemm_pipe<false, true, true><<<ggrid, 512, 0, stream>>>(
      bf1, Wt + (size_t)2 * D * D, R2, batch, bl, (float*)d_out, N, nTiles);
}